// Round 8
// baseline (480.625 us; speedup 1.0000x reference)
//
#include <hip/hip_runtime.h>
#include <stdint.h>

// ---------------------------------------------------------------------------
// MultiHeadAttentionWithRelativePosition  (B=8, H=16, L=768, D=1024, dk=64)
// R14: R12 exactly (passed, 289us) + attn launch_bounds (256,3)->(256,6).
// Grid is 6 blocks/CU and attn VGPR=60 fits the (256,6) cap (~85) -> whole
// grid co-resident, 6 waves/SIMD for the bperm->exp->PV chain.
// R13's cvt_pk+sigma P/V permutation REVERTED: failed absmax 3.45e-2, error
// magnitude consistent with lo/hi pack-order swap (key<->key+16 pairing) --
// unverifiable instruction semantics, needs disasm A/B before reuse.
// GEMMs keep R12 2-set register rotation; cast unchanged.
// ---------------------------------------------------------------------------

#define DEVFN static __device__ __forceinline__

typedef __bf16 bf16x8 __attribute__((ext_vector_type(8)));
typedef float f32x4 __attribute__((ext_vector_type(4)));

DEVFN uint16_t f2bf(float f) {
  uint32_t u = __builtin_bit_cast(uint32_t, f);
  u += 0x7fffu + ((u >> 16) & 1u);   // RNE
  return (uint16_t)(u >> 16);
}
DEVFN bf16x8 ldg8(const uint16_t* p) { return *reinterpret_cast<const bf16x8*>(p); }

DEVFN float bperm(int addr, float v) {
  return __builtin_bit_cast(float,
      __builtin_amdgcn_ds_bpermute(addr, __builtin_bit_cast(int, v)));
}

#define MFMA __builtin_amdgcn_mfma_f32_16x16x32_bf16

// ---------------- workspace layout (uint16 element offsets) ----------------
// XQ/XK/XV/WQ/WK/WV/WO are FRAG-LINEAR (same total sizes).
static const size_t OXQ = 0;
static const size_t OXK = 6291456;
static const size_t OXV = 12582912;
static const size_t OWQ = 18874368;
static const size_t OWK = 19922944;
static const size_t OWV = 20971520;
static const size_t OWO = 22020096;
static const size_t OEB = 23068672;   // 98304 elems (frag-linear E, 96 tiles)
static const size_t OQH = 23166976;
static const size_t OKH = 29458432;
static const size_t OVT = 35749888;
static const size_t OAO = 42041344;   // frag-linear (384 rr x 16384)

// ------------------------------ cast kernel --------------------------------
// Blocks [0,1408): one 16-row x 1024-col panel each -> frag-linear bf16.
//   XQ 384 | XK 384 | XV 384 | WQ 64 | WK 64 | WV 64 | WO 64
// Blocks [1408,1440): rel-pos E cast (unchanged layout).
__global__ __launch_bounds__(256) void cast_kernel(
    const float* __restrict__ q, const float* __restrict__ k, const float* __restrict__ v,
    const float* __restrict__ wq, const float* __restrict__ wk, const float* __restrict__ wv,
    const float* __restrict__ wo, const float* __restrict__ e, uint16_t* __restrict__ ws)
{
  const int bid = blockIdx.x;
  if (bid < 1408) {
    const float* src; size_t dofs; int rr;
    if (bid < 384)        { src = q;  dofs = OXQ; rr = bid; }
    else if (bid < 768)   { src = k;  dofs = OXK; rr = bid - 384; }
    else if (bid < 1152)  { src = v;  dofs = OXV; rr = bid - 768; }
    else {
      int w = bid - 1152; int m = w >> 6; rr = w & 63;
      src  = (m == 0) ? wq : (m == 1) ? wk : (m == 2) ? wv : wo;
      dofs = (m == 0) ? OWQ : (m == 1) ? OWK : (m == 2) ? OWV : OWO;
    }
    const int wavei = threadIdx.x >> 6, ln = threadIdx.x & 63;
    const int row = ln & 15, koff = (ln >> 4) * 8;
    const float* srow = src + (size_t)(rr * 16 + row) * 1024 + koff;
    uint16_t* dbase = ws + dofs + (size_t)rr * 16384 + ln * 8;
#pragma unroll
    for (int cc = 0; cc < 8; ++cc) {
      int t = wavei + cc * 4;            // 4 waves interleave k-chunks
      float4 f0 = *reinterpret_cast<const float4*>(srow + t * 32);
      float4 f1 = *reinterpret_cast<const float4*>(srow + t * 32 + 4);
      union { ushort4 u4[2]; uint16_t us[8]; } o;
      o.us[0] = f2bf(f0.x); o.us[1] = f2bf(f0.y); o.us[2] = f2bf(f0.z); o.us[3] = f2bf(f0.w);
      o.us[4] = f2bf(f1.x); o.us[5] = f2bf(f1.y); o.us[6] = f2bf(f1.z); o.us[7] = f2bf(f1.w);
      *reinterpret_cast<ushort4*>(dbase + t * 512)     = o.u4[0];
      *reinterpret_cast<ushort4*>(dbase + t * 512 + 4) = o.u4[1];
    }
  } else {
    // fragment-linear E: tile tau covers rel rows [16*tau, 16*tau+15]
    constexpr int NE4 = 98304 / 4;
    for (int i = (bid - 1408) * 256 + (int)threadIdx.x; i < NE4; i += 32 * 256) {
      ushort4 u;
#pragma unroll
      for (int t = 0; t < 4; ++t) {
        int o = i * 4 + t;
        int tau = o >> 10, r10 = o & 1023;
        int c = r10 >> 9, lane = (r10 >> 3) & 63, j = o & 7;
        int row = tau * 16 + (lane & 15);
        row = row > 1534 ? 1534 : row;
        int col = c * 32 + (lane >> 4) * 8 + j;
        ((uint16_t*)&u)[t] = f2bf(e[row * 64 + col]);
      }
      reinterpret_cast<ushort4*>(ws + OEB)[i] = u;
    }
  }
}

// --------------------- fused QKV projection GEMM (128x128) -----------------
// 1152 blocks: [0,384) Q-proj, [384,768) K-proj, [768,1152) V^T.
// XCD-local decode (R6). No LDS/barriers: frag-linear operands, each MFMA
// fragment is ONE contiguous 1KB coalesced wave-load. 2-set rotation.
__global__ __launch_bounds__(256, 3) void gemm_qkv(
    uint16_t* __restrict__ ws, const float* __restrict__ bq,
    const float* __restrict__ bk, const float* __restrict__ bv)
{
  const int f = blockIdx.x;
  const int mode = f / 384, t6 = f % 384;
  const int x = t6 & 7, u6 = t6 >> 3;   // u6 in [0,48)
  const uint16_t *A, *Bw; const float* bias; uint16_t* outp;
  int m0, n0;
  if (mode == 0)      { A = ws + OXQ; Bw = ws + OWQ; bias = bq; outp = ws + OQH;
                        m0 = (x * 6 + u6 % 6) * 128; n0 = (u6 / 6) * 128; }
  else if (mode == 1) { A = ws + OXK; Bw = ws + OWK; bias = bk; outp = ws + OKH;
                        m0 = (x * 6 + u6 % 6) * 128; n0 = (u6 / 6) * 128; }
  else                { A = ws + OWV; Bw = ws + OXV; bias = bv; outp = ws + OVT;
                        n0 = (x * 6 + u6 % 6) * 128; m0 = (u6 / 6) * 128; }

  const int tid = threadIdx.x, wave = tid >> 6, lane = tid & 63;
  const int quad = lane >> 4, lc = lane & 15;
  const int wm = __builtin_amdgcn_readfirstlane((wave >> 1) * 64);
  const int wn = __builtin_amdgcn_readfirstlane((wave & 1) * 64);
  const int lane8 = lane * 8;

  // SGPR bases (uniform) + single VGPR voffset (lane8)
  const uint16_t* Abase = A  + (size_t)((m0 + wm) >> 4) * 16384;
  const uint16_t* Bbase = Bw + (size_t)((n0 + wn) >> 4) * 16384;

  f32x4 acc[4][4];
#pragma unroll
  for (int i = 0; i < 4; ++i)
#pragma unroll
    for (int j = 0; j < 4; ++j) acc[i][j] = (f32x4){0.f, 0.f, 0.f, 0.f};

  bf16x8 a0[4], b0[4], a1[4], b1[4];
#pragma unroll
  for (int u = 0; u < 4; ++u) {
    a0[u] = ldg8(Abase + (size_t)u * 16384 + lane8);
    b0[u] = ldg8(Bbase + (size_t)u * 16384 + lane8);
  }

#pragma unroll 1
  for (int t = 0; t < 32; t += 2) {
    // prefetch tile t+1 into set1
#pragma unroll
    for (int u = 0; u < 4; ++u) {
      a1[u] = ldg8(Abase + (size_t)u * 16384 + (t + 1) * 512 + lane8);
      b1[u] = ldg8(Bbase + (size_t)u * 16384 + (t + 1) * 512 + lane8);
    }
    __builtin_amdgcn_sched_barrier(0);   // pin prefetch above MFMA cluster
    __builtin_amdgcn_s_setprio(1);
#pragma unroll
    for (int i = 0; i < 4; ++i)
#pragma unroll
      for (int j = 0; j < 4; ++j)
        acc[i][j] = MFMA(a0[i], b0[j], acc[i][j], 0, 0, 0);
    __builtin_amdgcn_s_setprio(0);
    // prefetch tile t+2 into set0 (clamped: last phase reloads tile 0, unused)
    const int t2 = (t + 2) & 31;
#pragma unroll
    for (int u = 0; u < 4; ++u) {
      a0[u] = ldg8(Abase + (size_t)u * 16384 + t2 * 512 + lane8);
      b0[u] = ldg8(Bbase + (size_t)u * 16384 + t2 * 512 + lane8);
    }
    __builtin_amdgcn_sched_barrier(0);
    __builtin_amdgcn_s_setprio(1);
#pragma unroll
    for (int i = 0; i < 4; ++i)
#pragma unroll
      for (int j = 0; j < 4; ++j)
        acc[i][j] = MFMA(a1[i], b1[j], acc[i][j], 0, 0, 0);
    __builtin_amdgcn_s_setprio(0);
  }

  const int bM = (m0 + wm) / 768;
  const int bN = n0 / 768;
#pragma unroll
  for (int i = 0; i < 4; ++i)
#pragma unroll
    for (int j = 0; j < 4; ++j)
#pragma unroll
      for (int r = 0; r < 4; ++r) {
        int mg = m0 + wm + i * 16 + quad * 4 + r;
        int ng = n0 + wn + j * 16 + lc;
        float v = acc[i][j][r];
        if (mode == 0) {
          v = (v + bias[ng]) * 0.125f;         // 1/sqrt(64) folded into Q
          int lr = mg - bM * 768;
          int h = ng >> 6, d = ng & 63;
          outp[(((size_t)(bM * 16 + h) * 768 + lr) << 6) + d] = f2bf(v);
        } else if (mode == 1) {
          // frag-linear K (attn layout, unchanged)
          v += bias[ng];
          int lr = mg - bM * 768;
          int h = ng >> 6, d = ng & 63;
          size_t flat = ((size_t)(bM * 16 + h) * 48 + (lr >> 4)) * 1024
                      + ((size_t)(d >> 5) << 9)
                      + ((((d >> 3) & 3) * 16 + (lr & 15)) << 3) + (d & 7);
          outp[flat] = f2bf(v);
        } else {
          // frag-linear V (attn layout, unchanged)
          v += bias[mg];
          int lr = ng - bN * 768;
          int h = mg >> 6, d = mg & 63;
          size_t flat = (size_t)(bN * 16 + h) * 49152
                      + (size_t)(lr >> 5) * 2048 + (size_t)(d >> 4) * 512
                      + ((((lr >> 3) & 3) * 16 + (d & 15)) << 3) + (lr & 7);
          outp[flat] = f2bf(v);
        }
      }
}

// ------------------------- O-projection GEMM (128x128) ---------------------
// 384 blocks, XCD-local. A = Ao frag-linear (written by attn), B = WO
// frag-linear. Same 2-set rotated structure.
__global__ __launch_bounds__(256, 3) void gemm_o(
    const uint16_t* __restrict__ A, const uint16_t* __restrict__ Bw,
    const float* __restrict__ bias, float* __restrict__ outp)
{
  const int t6 = blockIdx.x;
  const int x = t6 & 7, u6 = t6 >> 3;
  const int m0 = (x * 6 + u6 % 6) * 128, n0 = (u6 / 6) * 128;

  const int tid = threadIdx.x, wave = tid >> 6, lane = tid & 63;
  const int quad = lane >> 4, lc = lane & 15;
  const int wm = __builtin_amdgcn_readfirstlane((wave >> 1) * 64);
  const int wn = __builtin_amdgcn_readfirstlane((wave & 1) * 64);
  const int lane8 = lane * 8;

  const uint16_t* Abase = A  + (size_t)((m0 + wm) >> 4) * 16384;
  const uint16_t* Bbase = Bw + (size_t)((n0 + wn) >> 4) * 16384;

  f32x4 acc[4][4];
#pragma unroll
  for (int i = 0; i < 4; ++i)
#pragma unroll
    for (int j = 0; j < 4; ++j) acc[i][j] = (f32x4){0.f, 0.f, 0.f, 0.f};

  bf16x8 a0[4], b0[4], a1[4], b1[4];
#pragma unroll
  for (int u = 0; u < 4; ++u) {
    a0[u] = ldg8(Abase + (size_t)u * 16384 + lane8);
    b0[u] = ldg8(Bbase + (size_t)u * 16384 + lane8);
  }

#pragma unroll 1
  for (int t = 0; t < 32; t += 2) {
#pragma unroll
    for (int u = 0; u < 4; ++u) {
      a1[u] = ldg8(Abase + (size_t)u * 16384 + (t + 1) * 512 + lane8);
      b1[u] = ldg8(Bbase + (size_t)u * 16384 + (t + 1) * 512 + lane8);
    }
    __builtin_amdgcn_sched_barrier(0);
    __builtin_amdgcn_s_setprio(1);
#pragma unroll
    for (int i = 0; i < 4; ++i)
#pragma unroll
      for (int j = 0; j < 4; ++j)
        acc[i][j] = MFMA(a0[i], b0[j], acc[i][j], 0, 0, 0);
    __builtin_amdgcn_s_setprio(0);
    const int t2 = (t + 2) & 31;
#pragma unroll
    for (int u = 0; u < 4; ++u) {
      a0[u] = ldg8(Abase + (size_t)u * 16384 + t2 * 512 + lane8);
      b0[u] = ldg8(Bbase + (size_t)u * 16384 + t2 * 512 + lane8);
    }
    __builtin_amdgcn_sched_barrier(0);
    __builtin_amdgcn_s_setprio(1);
#pragma unroll
    for (int i = 0; i < 4; ++i)
#pragma unroll
      for (int j = 0; j < 4; ++j)
        acc[i][j] = MFMA(a1[i], b1[j], acc[i][j], 0, 0, 0);
    __builtin_amdgcn_s_setprio(0);
  }

#pragma unroll
  for (int i = 0; i < 4; ++i)
#pragma unroll
    for (int j = 0; j < 4; ++j)
#pragma unroll
      for (int r = 0; r < 4; ++r) {
        int mg = m0 + wm + i * 16 + quad * 4 + r;
        int ng = n0 + wn + j * 16 + lc;
        outp[(size_t)mg * 1024 + ng] = acc[i][j][r] + bias[ng];
      }
}

// ------------------------------ attention (flash) --------------------------
// R14: launch_bounds (256,6) -> whole grid co-resident (6 blocks/CU).
// R11 single-set load rotation; R12-identical numerics (f2bf P writes).
// Epilogue writes Ao FRAG-LINEAR.
__global__ __launch_bounds__(256, 6) void attn_kernel(
    const uint16_t* __restrict__ Qh, const uint16_t* __restrict__ KTf,
    const uint16_t* __restrict__ VTf, const uint16_t* __restrict__ Et,
    uint16_t* __restrict__ Ao)
{
  constexpr int L = 768, DK = 64;
  __shared__ uint16_t Pb[4][16][40];
  const int wave = threadIdx.x >> 6, lane = threadIdx.x & 63;
  const int quad = lane >> 4, lc = lane & 15;
  const int f = blockIdx.x, g = f >> 3;
  const int bh = (f & 7) * 16 + (g & 15);
  const int q0 = ((g >> 4) * 4 + wave) * 16;
  const int lane8 = lane * 8;

  const uint16_t* Qp = Qh + ((size_t)bh * L + q0) * DK;
  bf16x8 qf0 = ldg8(Qp + lc * DK + quad * 8);
  bf16x8 qf1 = ldg8(Qp + lc * DK + 32 + quad * 8);

  int addr_r[4]; bool sel_r[4];
#pragma unroll
  for (int r = 0; r < 4; ++r) {
    int qi = quad * 4 + r;
    int t = lc - qi + 15;
    addr_r[r] = (quad * 16 + (t & 15)) * 4;
    sel_r[r] = t >= 16;
  }

  float l_r[4] = {0.f, 0.f, 0.f, 0.f};
  f32x4 o[4];
#pragma unroll
  for (int t = 0; t < 4; ++t) o[t] = (f32x4){0.f, 0.f, 0.f, 0.f};

  const uint16_t* Kb = KTf + (size_t)bh * 48 * 1024;
  const uint16_t* Vb = VTf + (size_t)bh * 49152;
  const int taubase = 47 - (q0 >> 4);

  // rotated register state (single set, reloaded after last use)
  bf16x8 kf0, kf1, kf2, kf3, ef0, ef1, ef2, ef3, vf0, vf1, vf2, vf3;
  {
    const uint16_t* kp = Kb + lane8;
    kf0 = ldg8(kp); kf1 = ldg8(kp + 512); kf2 = ldg8(kp + 1024); kf3 = ldg8(kp + 1536);
    const uint16_t* ep = Et + (size_t)(taubase + 1) * 1024 + lane8;
    ef0 = ldg8(ep); ef1 = ldg8(ep + 512); ef2 = ldg8(ep + 1024); ef3 = ldg8(ep + 1536);
    const uint16_t* vp = Vb + lane8;
    vf0 = ldg8(vp); vf1 = ldg8(vp + 512); vf2 = ldg8(vp + 1024); vf3 = ldg8(vp + 1536);
  }

  // prologue: E-tile tau = taubase (becomes w0 of kb=0)
  f32x4 wcarry;
  {
    const uint16_t* ep = Et + (size_t)taubase * 1024 + lane8;
    bf16x8 p0 = ldg8(ep), p1 = ldg8(ep + 512);
    f32x4 a = (f32x4){0.f, 0.f, 0.f, 0.f};
    a = MFMA(qf0, p0, a, 0, 0, 0);
    a = MFMA(qf1, p1, a, 0, 0, 0);
    wcarry = a;
  }

#pragma unroll 1
  for (int kb = 0; kb < 24; ++kb) {
    const int kbn = (kb + 1 < 24) ? kb + 1 : 23;   // clamp: last reload redundant

    f32x4 s0 = (f32x4){0.f, 0.f, 0.f, 0.f}, s1 = s0, w1 = s0, w2 = s0;
    __builtin_amdgcn_s_setprio(1);
    s0 = MFMA(qf0, kf0, s0, 0, 0, 0);
    s0 = MFMA(qf1, kf1, s0, 0, 0, 0);
    s1 = MFMA(qf0, kf2, s1, 0, 0, 0);
    s1 = MFMA(qf1, kf3, s1, 0, 0, 0);
    w1 = MFMA(qf0, ef0, w1, 0, 0, 0);
    w1 = MFMA(qf1, ef1, w1, 0, 0, 0);
    w2 = MFMA(qf0, ef2, w2, 0, 0, 0);
    w2 = MFMA(qf1, ef3, w2, 0, 0, 0);
    __builtin_amdgcn_s_setprio(0);

    // reload K/E for kb+1 (regs dead after MFMAs above; WAR-safe in-order)
    {
      const uint16_t* kp = Kb + (size_t)(2 * kbn) * 1024 + lane8;
      kf0 = ldg8(kp); kf1 = ldg8(kp + 512); kf2 = ldg8(kp + 1024); kf3 = ldg8(kp + 1536);
      const uint16_t* ep = Et + (size_t)(taubase + 2 * kbn + 1) * 1024 + lane8;
      ef0 = ldg8(ep); ef1 = ldg8(ep + 512); ef2 = ldg8(ep + 1024); ef3 = ldg8(ep + 1536);
    }
    __builtin_amdgcn_sched_barrier(0);   // pin reloads above the softmax chain

#pragma unroll
    for (int r = 0; r < 4; ++r) {
      float v0a  = bperm(addr_r[r], wcarry[r]);
      float vmid = bperm(addr_r[r], w1[r]);
      float v1b  = bperm(addr_r[r], w2[r]);
      float e0 = __expf(s0[r] + (sel_r[r] ? vmid : v0a));
      float e1 = __expf(s1[r] + (sel_r[r] ? v1b : vmid));
      l_r[r] += e0 + e1;
      int qi = quad * 4 + r;
      Pb[wave][qi][lc]      = f2bf(e0);
      Pb[wave][qi][16 + lc] = f2bf(e1);
    }
    wcarry = w2;

    __builtin_amdgcn_s_waitcnt(0xC07F);   // lgkmcnt(0), wave-local

    bf16x8 af = *reinterpret_cast<const bf16x8*>(&Pb[wave][lc][quad * 8]);
    __builtin_amdgcn_s_setprio(1);
    o[0] = MFMA(af, vf0, o[0], 0, 0, 0);
    o[1] = MFMA(af, vf1, o[1], 0, 0, 0);
    o[2] = MFMA(af, vf2, o[2], 0, 0, 0);
    o[3] = MFMA(af, vf3, o[3], 0, 0, 0);
    __builtin_amdgcn_s_setprio(0);

    // reload V for kb+1 (regs dead after PV above)
    {
      const uint16_t* vp = Vb + (size_t)kbn * 2048 + lane8;
      vf0 = ldg8(vp); vf1 = ldg8(vp + 512); vf2 = ldg8(vp + 1024); vf3 = ldg8(vp + 1536);
    }
  }

#pragma unroll
  for (int r = 0; r < 4; ++r) {
    float l = l_r[r];
    l += __shfl_xor(l, 1, 64);
    l += __shfl_xor(l, 2, 64);
    l += __shfl_xor(l, 4, 64);
    l += __shfl_xor(l, 8, 64);
    l_r[r] = 1.0f / l;
  }

  const int b = bh >> 4, h = bh & 15;
  const size_t rrbase = (size_t)((b * L + q0) >> 4) * 16384;
#pragma unroll
  for (int r = 0; r < 4; ++r) {
    int qi = quad * 4 + r;
#pragma unroll
    for (int nt = 0; nt < 4; ++nt) {
      int col = h * 64 + nt * 16 + lc;
      size_t flat = rrbase + (size_t)(col >> 5) * 512 + ((col >> 3) & 3) * 128
                  + qi * 8 + (col & 7);
      Ao[flat] = f2bf(o[nt][r] * l_r[r]);
    }
  }
}

// ------------------------------ launcher -----------------------------------
extern "C" void kernel_launch(void* const* d_in, const int* in_sizes, int n_in,
                              void* d_out, int out_size, void* d_ws, size_t ws_size,
                              hipStream_t stream) {
  const float* q   = (const float*)d_in[0];
  const float* k   = (const float*)d_in[1];
  const float* v   = (const float*)d_in[2];
  const float* b_q = (const float*)d_in[4];
  const float* b_k = (const float*)d_in[6];
  const float* b_v = (const float*)d_in[8];
  const float* b_o = (const float*)d_in[10];
  uint16_t* ws = (uint16_t*)d_ws;

  cast_kernel<<<1440, 256, 0, stream>>>(q, k, v,
      (const float*)d_in[3], (const float*)d_in[5], (const float*)d_in[7],
      (const float*)d_in[9], (const float*)d_in[11], ws);

  gemm_qkv<<<1152, 256, 0, stream>>>(ws, b_q, b_k, b_v);

  attn_kernel<<<1536, 256, 0, stream>>>(ws + OQH, ws + OKH, ws + OVT, ws + OEB, ws + OAO);

  gemm_o<<<384, 256, 0, stream>>>(ws + OAO, ws + OWO, b_o, (float*)d_out);
}

// Round 9
// 281.855 us; speedup vs baseline: 1.7052x; 1.7052x over previous
//
#include <hip/hip_runtime.h>
#include <stdint.h>

// ---------------------------------------------------------------------------
// MultiHeadAttentionWithRelativePosition  (B=8, H=16, L=768, D=1024, dk=64)
// R15: R12 exactly (passed, 289us) + attn launch_bounds (256,4).
// R14's (256,6) FAILED: HW reg-alloc quantum steps at {64,128,256} -> 6
// waves/EU forced a 64-reg cap -> 12 frag regs spilled to scratch -> 1GB HBM
// spill traffic, attn 70->260us. (256,4) caps at 128 regs (kernel uses ~76
// unified, no spill) and gives 4 blocks/CU co-resident (was 3): 6-blocks/CU
// workload makespan 2 rounds -> 1.5 rounds + deeper per-round TLP.
// GEMMs keep R12 2-set register rotation; cast unchanged.
// ---------------------------------------------------------------------------

#define DEVFN static __device__ __forceinline__

typedef __bf16 bf16x8 __attribute__((ext_vector_type(8)));
typedef float f32x4 __attribute__((ext_vector_type(4)));

DEVFN uint16_t f2bf(float f) {
  uint32_t u = __builtin_bit_cast(uint32_t, f);
  u += 0x7fffu + ((u >> 16) & 1u);   // RNE
  return (uint16_t)(u >> 16);
}
DEVFN bf16x8 ldg8(const uint16_t* p) { return *reinterpret_cast<const bf16x8*>(p); }

DEVFN float bperm(int addr, float v) {
  return __builtin_bit_cast(float,
      __builtin_amdgcn_ds_bpermute(addr, __builtin_bit_cast(int, v)));
}

#define MFMA __builtin_amdgcn_mfma_f32_16x16x32_bf16

// ---------------- workspace layout (uint16 element offsets) ----------------
// XQ/XK/XV/WQ/WK/WV/WO are FRAG-LINEAR (same total sizes).
static const size_t OXQ = 0;
static const size_t OXK = 6291456;
static const size_t OXV = 12582912;
static const size_t OWQ = 18874368;
static const size_t OWK = 19922944;
static const size_t OWV = 20971520;
static const size_t OWO = 22020096;
static const size_t OEB = 23068672;   // 98304 elems (frag-linear E, 96 tiles)
static const size_t OQH = 23166976;
static const size_t OKH = 29458432;
static const size_t OVT = 35749888;
static const size_t OAO = 42041344;   // frag-linear (384 rr x 16384)

// ------------------------------ cast kernel --------------------------------
// Blocks [0,1408): one 16-row x 1024-col panel each -> frag-linear bf16.
//   XQ 384 | XK 384 | XV 384 | WQ 64 | WK 64 | WV 64 | WO 64
// Blocks [1408,1440): rel-pos E cast (unchanged layout).
__global__ __launch_bounds__(256) void cast_kernel(
    const float* __restrict__ q, const float* __restrict__ k, const float* __restrict__ v,
    const float* __restrict__ wq, const float* __restrict__ wk, const float* __restrict__ wv,
    const float* __restrict__ wo, const float* __restrict__ e, uint16_t* __restrict__ ws)
{
  const int bid = blockIdx.x;
  if (bid < 1408) {
    const float* src; size_t dofs; int rr;
    if (bid < 384)        { src = q;  dofs = OXQ; rr = bid; }
    else if (bid < 768)   { src = k;  dofs = OXK; rr = bid - 384; }
    else if (bid < 1152)  { src = v;  dofs = OXV; rr = bid - 768; }
    else {
      int w = bid - 1152; int m = w >> 6; rr = w & 63;
      src  = (m == 0) ? wq : (m == 1) ? wk : (m == 2) ? wv : wo;
      dofs = (m == 0) ? OWQ : (m == 1) ? OWK : (m == 2) ? OWV : OWO;
    }
    const int wavei = threadIdx.x >> 6, ln = threadIdx.x & 63;
    const int row = ln & 15, koff = (ln >> 4) * 8;
    const float* srow = src + (size_t)(rr * 16 + row) * 1024 + koff;
    uint16_t* dbase = ws + dofs + (size_t)rr * 16384 + ln * 8;
#pragma unroll
    for (int cc = 0; cc < 8; ++cc) {
      int t = wavei + cc * 4;            // 4 waves interleave k-chunks
      float4 f0 = *reinterpret_cast<const float4*>(srow + t * 32);
      float4 f1 = *reinterpret_cast<const float4*>(srow + t * 32 + 4);
      union { ushort4 u4[2]; uint16_t us[8]; } o;
      o.us[0] = f2bf(f0.x); o.us[1] = f2bf(f0.y); o.us[2] = f2bf(f0.z); o.us[3] = f2bf(f0.w);
      o.us[4] = f2bf(f1.x); o.us[5] = f2bf(f1.y); o.us[6] = f2bf(f1.z); o.us[7] = f2bf(f1.w);
      *reinterpret_cast<ushort4*>(dbase + t * 512)     = o.u4[0];
      *reinterpret_cast<ushort4*>(dbase + t * 512 + 4) = o.u4[1];
    }
  } else {
    // fragment-linear E: tile tau covers rel rows [16*tau, 16*tau+15]
    constexpr int NE4 = 98304 / 4;
    for (int i = (bid - 1408) * 256 + (int)threadIdx.x; i < NE4; i += 32 * 256) {
      ushort4 u;
#pragma unroll
      for (int t = 0; t < 4; ++t) {
        int o = i * 4 + t;
        int tau = o >> 10, r10 = o & 1023;
        int c = r10 >> 9, lane = (r10 >> 3) & 63, j = o & 7;
        int row = tau * 16 + (lane & 15);
        row = row > 1534 ? 1534 : row;
        int col = c * 32 + (lane >> 4) * 8 + j;
        ((uint16_t*)&u)[t] = f2bf(e[row * 64 + col]);
      }
      reinterpret_cast<ushort4*>(ws + OEB)[i] = u;
    }
  }
}

// --------------------- fused QKV projection GEMM (128x128) -----------------
// 1152 blocks: [0,384) Q-proj, [384,768) K-proj, [768,1152) V^T.
// XCD-local decode (R6). No LDS/barriers: frag-linear operands, each MFMA
// fragment is ONE contiguous 1KB coalesced wave-load. 2-set rotation.
__global__ __launch_bounds__(256, 3) void gemm_qkv(
    uint16_t* __restrict__ ws, const float* __restrict__ bq,
    const float* __restrict__ bk, const float* __restrict__ bv)
{
  const int f = blockIdx.x;
  const int mode = f / 384, t6 = f % 384;
  const int x = t6 & 7, u6 = t6 >> 3;   // u6 in [0,48)
  const uint16_t *A, *Bw; const float* bias; uint16_t* outp;
  int m0, n0;
  if (mode == 0)      { A = ws + OXQ; Bw = ws + OWQ; bias = bq; outp = ws + OQH;
                        m0 = (x * 6 + u6 % 6) * 128; n0 = (u6 / 6) * 128; }
  else if (mode == 1) { A = ws + OXK; Bw = ws + OWK; bias = bk; outp = ws + OKH;
                        m0 = (x * 6 + u6 % 6) * 128; n0 = (u6 / 6) * 128; }
  else                { A = ws + OWV; Bw = ws + OXV; bias = bv; outp = ws + OVT;
                        n0 = (x * 6 + u6 % 6) * 128; m0 = (u6 / 6) * 128; }

  const int tid = threadIdx.x, wave = tid >> 6, lane = tid & 63;
  const int quad = lane >> 4, lc = lane & 15;
  const int wm = __builtin_amdgcn_readfirstlane((wave >> 1) * 64);
  const int wn = __builtin_amdgcn_readfirstlane((wave & 1) * 64);
  const int lane8 = lane * 8;

  // SGPR bases (uniform) + single VGPR voffset (lane8)
  const uint16_t* Abase = A  + (size_t)((m0 + wm) >> 4) * 16384;
  const uint16_t* Bbase = Bw + (size_t)((n0 + wn) >> 4) * 16384;

  f32x4 acc[4][4];
#pragma unroll
  for (int i = 0; i < 4; ++i)
#pragma unroll
    for (int j = 0; j < 4; ++j) acc[i][j] = (f32x4){0.f, 0.f, 0.f, 0.f};

  bf16x8 a0[4], b0[4], a1[4], b1[4];
#pragma unroll
  for (int u = 0; u < 4; ++u) {
    a0[u] = ldg8(Abase + (size_t)u * 16384 + lane8);
    b0[u] = ldg8(Bbase + (size_t)u * 16384 + lane8);
  }

#pragma unroll 1
  for (int t = 0; t < 32; t += 2) {
    // prefetch tile t+1 into set1
#pragma unroll
    for (int u = 0; u < 4; ++u) {
      a1[u] = ldg8(Abase + (size_t)u * 16384 + (t + 1) * 512 + lane8);
      b1[u] = ldg8(Bbase + (size_t)u * 16384 + (t + 1) * 512 + lane8);
    }
    __builtin_amdgcn_sched_barrier(0);   // pin prefetch above MFMA cluster
    __builtin_amdgcn_s_setprio(1);
#pragma unroll
    for (int i = 0; i < 4; ++i)
#pragma unroll
      for (int j = 0; j < 4; ++j)
        acc[i][j] = MFMA(a0[i], b0[j], acc[i][j], 0, 0, 0);
    __builtin_amdgcn_s_setprio(0);
    // prefetch tile t+2 into set0 (clamped: last phase reloads tile 0, unused)
    const int t2 = (t + 2) & 31;
#pragma unroll
    for (int u = 0; u < 4; ++u) {
      a0[u] = ldg8(Abase + (size_t)u * 16384 + t2 * 512 + lane8);
      b0[u] = ldg8(Bbase + (size_t)u * 16384 + t2 * 512 + lane8);
    }
    __builtin_amdgcn_sched_barrier(0);
    __builtin_amdgcn_s_setprio(1);
#pragma unroll
    for (int i = 0; i < 4; ++i)
#pragma unroll
      for (int j = 0; j < 4; ++j)
        acc[i][j] = MFMA(a1[i], b1[j], acc[i][j], 0, 0, 0);
    __builtin_amdgcn_s_setprio(0);
  }

  const int bM = (m0 + wm) / 768;
  const int bN = n0 / 768;
#pragma unroll
  for (int i = 0; i < 4; ++i)
#pragma unroll
    for (int j = 0; j < 4; ++j)
#pragma unroll
      for (int r = 0; r < 4; ++r) {
        int mg = m0 + wm + i * 16 + quad * 4 + r;
        int ng = n0 + wn + j * 16 + lc;
        float v = acc[i][j][r];
        if (mode == 0) {
          v = (v + bias[ng]) * 0.125f;         // 1/sqrt(64) folded into Q
          int lr = mg - bM * 768;
          int h = ng >> 6, d = ng & 63;
          outp[(((size_t)(bM * 16 + h) * 768 + lr) << 6) + d] = f2bf(v);
        } else if (mode == 1) {
          // frag-linear K (attn layout, unchanged)
          v += bias[ng];
          int lr = mg - bM * 768;
          int h = ng >> 6, d = ng & 63;
          size_t flat = ((size_t)(bM * 16 + h) * 48 + (lr >> 4)) * 1024
                      + ((size_t)(d >> 5) << 9)
                      + ((((d >> 3) & 3) * 16 + (lr & 15)) << 3) + (d & 7);
          outp[flat] = f2bf(v);
        } else {
          // frag-linear V (attn layout, unchanged)
          v += bias[mg];
          int lr = ng - bN * 768;
          int h = mg >> 6, d = mg & 63;
          size_t flat = (size_t)(bN * 16 + h) * 49152
                      + (size_t)(lr >> 5) * 2048 + (size_t)(d >> 4) * 512
                      + ((((lr >> 3) & 3) * 16 + (d & 15)) << 3) + (lr & 7);
          outp[flat] = f2bf(v);
        }
      }
}

// ------------------------- O-projection GEMM (128x128) ---------------------
// 384 blocks, XCD-local. A = Ao frag-linear (written by attn), B = WO
// frag-linear. Same 2-set rotated structure.
__global__ __launch_bounds__(256, 3) void gemm_o(
    const uint16_t* __restrict__ A, const uint16_t* __restrict__ Bw,
    const float* __restrict__ bias, float* __restrict__ outp)
{
  const int t6 = blockIdx.x;
  const int x = t6 & 7, u6 = t6 >> 3;
  const int m0 = (x * 6 + u6 % 6) * 128, n0 = (u6 / 6) * 128;

  const int tid = threadIdx.x, wave = tid >> 6, lane = tid & 63;
  const int quad = lane >> 4, lc = lane & 15;
  const int wm = __builtin_amdgcn_readfirstlane((wave >> 1) * 64);
  const int wn = __builtin_amdgcn_readfirstlane((wave & 1) * 64);
  const int lane8 = lane * 8;

  const uint16_t* Abase = A  + (size_t)((m0 + wm) >> 4) * 16384;
  const uint16_t* Bbase = Bw + (size_t)((n0 + wn) >> 4) * 16384;

  f32x4 acc[4][4];
#pragma unroll
  for (int i = 0; i < 4; ++i)
#pragma unroll
    for (int j = 0; j < 4; ++j) acc[i][j] = (f32x4){0.f, 0.f, 0.f, 0.f};

  bf16x8 a0[4], b0[4], a1[4], b1[4];
#pragma unroll
  for (int u = 0; u < 4; ++u) {
    a0[u] = ldg8(Abase + (size_t)u * 16384 + lane8);
    b0[u] = ldg8(Bbase + (size_t)u * 16384 + lane8);
  }

#pragma unroll 1
  for (int t = 0; t < 32; t += 2) {
#pragma unroll
    for (int u = 0; u < 4; ++u) {
      a1[u] = ldg8(Abase + (size_t)u * 16384 + (t + 1) * 512 + lane8);
      b1[u] = ldg8(Bbase + (size_t)u * 16384 + (t + 1) * 512 + lane8);
    }
    __builtin_amdgcn_sched_barrier(0);
    __builtin_amdgcn_s_setprio(1);
#pragma unroll
    for (int i = 0; i < 4; ++i)
#pragma unroll
      for (int j = 0; j < 4; ++j)
        acc[i][j] = MFMA(a0[i], b0[j], acc[i][j], 0, 0, 0);
    __builtin_amdgcn_s_setprio(0);
    const int t2 = (t + 2) & 31;
#pragma unroll
    for (int u = 0; u < 4; ++u) {
      a0[u] = ldg8(Abase + (size_t)u * 16384 + t2 * 512 + lane8);
      b0[u] = ldg8(Bbase + (size_t)u * 16384 + t2 * 512 + lane8);
    }
    __builtin_amdgcn_sched_barrier(0);
    __builtin_amdgcn_s_setprio(1);
#pragma unroll
    for (int i = 0; i < 4; ++i)
#pragma unroll
      for (int j = 0; j < 4; ++j)
        acc[i][j] = MFMA(a1[i], b1[j], acc[i][j], 0, 0, 0);
    __builtin_amdgcn_s_setprio(0);
  }

#pragma unroll
  for (int i = 0; i < 4; ++i)
#pragma unroll
    for (int j = 0; j < 4; ++j)
#pragma unroll
      for (int r = 0; r < 4; ++r) {
        int mg = m0 + wm + i * 16 + quad * 4 + r;
        int ng = n0 + wn + j * 16 + lc;
        outp[(size_t)mg * 1024 + ng] = acc[i][j][r] + bias[ng];
      }
}

// ------------------------------ attention (flash) --------------------------
// R15: launch_bounds (256,4) -> 4 blocks/CU co-resident, 128-reg cap (no
// spill; R14's (256,6) forced 64-reg cap -> 1GB scratch traffic).
// R11 single-set load rotation; R12-identical numerics (f2bf P writes).
// Epilogue writes Ao FRAG-LINEAR.
__global__ __launch_bounds__(256, 4) void attn_kernel(
    const uint16_t* __restrict__ Qh, const uint16_t* __restrict__ KTf,
    const uint16_t* __restrict__ VTf, const uint16_t* __restrict__ Et,
    uint16_t* __restrict__ Ao)
{
  constexpr int L = 768, DK = 64;
  __shared__ uint16_t Pb[4][16][40];
  const int wave = threadIdx.x >> 6, lane = threadIdx.x & 63;
  const int quad = lane >> 4, lc = lane & 15;
  const int f = blockIdx.x, g = f >> 3;
  const int bh = (f & 7) * 16 + (g & 15);
  const int q0 = ((g >> 4) * 4 + wave) * 16;
  const int lane8 = lane * 8;

  const uint16_t* Qp = Qh + ((size_t)bh * L + q0) * DK;
  bf16x8 qf0 = ldg8(Qp + lc * DK + quad * 8);
  bf16x8 qf1 = ldg8(Qp + lc * DK + 32 + quad * 8);

  int addr_r[4]; bool sel_r[4];
#pragma unroll
  for (int r = 0; r < 4; ++r) {
    int qi = quad * 4 + r;
    int t = lc - qi + 15;
    addr_r[r] = (quad * 16 + (t & 15)) * 4;
    sel_r[r] = t >= 16;
  }

  float l_r[4] = {0.f, 0.f, 0.f, 0.f};
  f32x4 o[4];
#pragma unroll
  for (int t = 0; t < 4; ++t) o[t] = (f32x4){0.f, 0.f, 0.f, 0.f};

  const uint16_t* Kb = KTf + (size_t)bh * 48 * 1024;
  const uint16_t* Vb = VTf + (size_t)bh * 49152;
  const int taubase = 47 - (q0 >> 4);

  // rotated register state (single set, reloaded after last use)
  bf16x8 kf0, kf1, kf2, kf3, ef0, ef1, ef2, ef3, vf0, vf1, vf2, vf3;
  {
    const uint16_t* kp = Kb + lane8;
    kf0 = ldg8(kp); kf1 = ldg8(kp + 512); kf2 = ldg8(kp + 1024); kf3 = ldg8(kp + 1536);
    const uint16_t* ep = Et + (size_t)(taubase + 1) * 1024 + lane8;
    ef0 = ldg8(ep); ef1 = ldg8(ep + 512); ef2 = ldg8(ep + 1024); ef3 = ldg8(ep + 1536);
    const uint16_t* vp = Vb + lane8;
    vf0 = ldg8(vp); vf1 = ldg8(vp + 512); vf2 = ldg8(vp + 1024); vf3 = ldg8(vp + 1536);
  }

  // prologue: E-tile tau = taubase (becomes w0 of kb=0)
  f32x4 wcarry;
  {
    const uint16_t* ep = Et + (size_t)taubase * 1024 + lane8;
    bf16x8 p0 = ldg8(ep), p1 = ldg8(ep + 512);
    f32x4 a = (f32x4){0.f, 0.f, 0.f, 0.f};
    a = MFMA(qf0, p0, a, 0, 0, 0);
    a = MFMA(qf1, p1, a, 0, 0, 0);
    wcarry = a;
  }

#pragma unroll 1
  for (int kb = 0; kb < 24; ++kb) {
    const int kbn = (kb + 1 < 24) ? kb + 1 : 23;   // clamp: last reload redundant

    f32x4 s0 = (f32x4){0.f, 0.f, 0.f, 0.f}, s1 = s0, w1 = s0, w2 = s0;
    __builtin_amdgcn_s_setprio(1);
    s0 = MFMA(qf0, kf0, s0, 0, 0, 0);
    s0 = MFMA(qf1, kf1, s0, 0, 0, 0);
    s1 = MFMA(qf0, kf2, s1, 0, 0, 0);
    s1 = MFMA(qf1, kf3, s1, 0, 0, 0);
    w1 = MFMA(qf0, ef0, w1, 0, 0, 0);
    w1 = MFMA(qf1, ef1, w1, 0, 0, 0);
    w2 = MFMA(qf0, ef2, w2, 0, 0, 0);
    w2 = MFMA(qf1, ef3, w2, 0, 0, 0);
    __builtin_amdgcn_s_setprio(0);

    // reload K/E for kb+1 (regs dead after MFMAs above; WAR-safe in-order)
    {
      const uint16_t* kp = Kb + (size_t)(2 * kbn) * 1024 + lane8;
      kf0 = ldg8(kp); kf1 = ldg8(kp + 512); kf2 = ldg8(kp + 1024); kf3 = ldg8(kp + 1536);
      const uint16_t* ep = Et + (size_t)(taubase + 2 * kbn + 1) * 1024 + lane8;
      ef0 = ldg8(ep); ef1 = ldg8(ep + 512); ef2 = ldg8(ep + 1024); ef3 = ldg8(ep + 1536);
    }
    __builtin_amdgcn_sched_barrier(0);   // pin reloads above the softmax chain

#pragma unroll
    for (int r = 0; r < 4; ++r) {
      float v0a  = bperm(addr_r[r], wcarry[r]);
      float vmid = bperm(addr_r[r], w1[r]);
      float v1b  = bperm(addr_r[r], w2[r]);
      float e0 = __expf(s0[r] + (sel_r[r] ? vmid : v0a));
      float e1 = __expf(s1[r] + (sel_r[r] ? v1b : vmid));
      l_r[r] += e0 + e1;
      int qi = quad * 4 + r;
      Pb[wave][qi][lc]      = f2bf(e0);
      Pb[wave][qi][16 + lc] = f2bf(e1);
    }
    wcarry = w2;

    __builtin_amdgcn_s_waitcnt(0xC07F);   // lgkmcnt(0), wave-local

    bf16x8 af = *reinterpret_cast<const bf16x8*>(&Pb[wave][lc][quad * 8]);
    __builtin_amdgcn_s_setprio(1);
    o[0] = MFMA(af, vf0, o[0], 0, 0, 0);
    o[1] = MFMA(af, vf1, o[1], 0, 0, 0);
    o[2] = MFMA(af, vf2, o[2], 0, 0, 0);
    o[3] = MFMA(af, vf3, o[3], 0, 0, 0);
    __builtin_amdgcn_s_setprio(0);

    // reload V for kb+1 (regs dead after PV above)
    {
      const uint16_t* vp = Vb + (size_t)kbn * 2048 + lane8;
      vf0 = ldg8(vp); vf1 = ldg8(vp + 512); vf2 = ldg8(vp + 1024); vf3 = ldg8(vp + 1536);
    }
  }

#pragma unroll
  for (int r = 0; r < 4; ++r) {
    float l = l_r[r];
    l += __shfl_xor(l, 1, 64);
    l += __shfl_xor(l, 2, 64);
    l += __shfl_xor(l, 4, 64);
    l += __shfl_xor(l, 8, 64);
    l_r[r] = 1.0f / l;
  }

  const int b = bh >> 4, h = bh & 15;
  const size_t rrbase = (size_t)((b * L + q0) >> 4) * 16384;
#pragma unroll
  for (int r = 0; r < 4; ++r) {
    int qi = quad * 4 + r;
#pragma unroll
    for (int nt = 0; nt < 4; ++nt) {
      int col = h * 64 + nt * 16 + lc;
      size_t flat = rrbase + (size_t)(col >> 5) * 512 + ((col >> 3) & 3) * 128
                  + qi * 8 + (col & 7);
      Ao[flat] = f2bf(o[nt][r] * l_r[r]);
    }
  }
}

// ------------------------------ launcher -----------------------------------
extern "C" void kernel_launch(void* const* d_in, const int* in_sizes, int n_in,
                              void* d_out, int out_size, void* d_ws, size_t ws_size,
                              hipStream_t stream) {
  const float* q   = (const float*)d_in[0];
  const float* k   = (const float*)d_in[1];
  const float* v   = (const float*)d_in[2];
  const float* b_q = (const float*)d_in[4];
  const float* b_k = (const float*)d_in[6];
  const float* b_v = (const float*)d_in[8];
  const float* b_o = (const float*)d_in[10];
  uint16_t* ws = (uint16_t*)d_ws;

  cast_kernel<<<1440, 256, 0, stream>>>(q, k, v,
      (const float*)d_in[3], (const float*)d_in[5], (const float*)d_in[7],
      (const float*)d_in[9], (const float*)d_in[11], ws);

  gemm_qkv<<<1152, 256, 0, stream>>>(ws, b_q, b_k, b_v);

  attn_kernel<<<1536, 256, 0, stream>>>(ws + OQH, ws + OKH, ws + OVT, ws + OEB, ws + OAO);

  gemm_o<<<384, 256, 0, stream>>>(ws + OAO, ws + OWO, b_o, (float*)d_out);
}